// Round 4
// baseline (108.771 us; speedup 1.0000x reference)
//
#include <hip/hip_runtime.h>
#include <hip/hip_bf16.h>

#define BATCH 2048
#define NCLS  1000
#define FEAT  128

typedef short bf16x8 __attribute__((ext_vector_type(8)));
typedef float f32x4  __attribute__((ext_vector_type(4)));

// ws float layout (12.5 KB total — no big staging buffers, see R3 post-mortem):
//   [0]                 likelihood accumulator (fp32)
//   [64   .. 64+2048)   fn[b] = |feat_b|^2   (fp32)
//   [2112 .. 2112+1000) cn[c] = |center_c|^2 (fp32)
#define WS_FN   64
#define WS_CN   2112

__device__ inline short f2bf(float f) {
    unsigned int u;
    __builtin_memcpy(&u, &f, 4);
    unsigned int r = u + 0x7fffu + ((u >> 16) & 1u);   // RNE
    return (short)(r >> 16);
}

// One wave per row: rows 0..2047 = feat rows (norm + likelihood),
// rows 2048..3047 = center rows (norm). 64 lanes x 2 elems = 128.
__global__ __launch_bounds__(256) void prep_kernel(
    const float* __restrict__ feat,
    const float* __restrict__ centers,
    const int* __restrict__ label,
    float* __restrict__ ws)
{
    int w    = blockIdx.x * 4 + (threadIdx.x >> 6);
    int lane = threadIdx.x & 63;
    float* fn = ws + WS_FN;
    float* cn = ws + WS_CN;

    if (w < BATCH) {
        int b = w;
        float2 f = *(const float2*)(feat + b * FEAT + lane * 2);
        int lb = label[b];
        float2 c = *(const float2*)(centers + lb * FEAT + lane * 2);
        float fs = f.x * f.x + f.y * f.y;
        float d0 = f.x - c.x, d1 = f.y - c.y;
        float ls = d0 * d0 + d1 * d1;
        #pragma unroll
        for (int off = 32; off > 0; off >>= 1) {
            fs += __shfl_down(fs, off, 64);
            ls += __shfl_down(ls, off, 64);
        }
        if (lane == 0) {
            fn[b] = fs;
            atomicAdd(ws, ls * (0.5f / (float)BATCH));
        }
    } else if (w < BATCH + NCLS) {
        int c = w - BATCH;
        float2 cv = *(const float2*)(centers + c * FEAT + lane * 2);
        float cs = cv.x * cv.x + cv.y * cv.y;
        #pragma unroll
        for (int off = 32; off > 0; off >>= 1) cs += __shfl_down(cs, off, 64);
        if (lane == 0) cn[c] = cs;
    }
}

__device__ inline bf16x8 load_cvt8(const float* p) {
    f32x4 v0 = *(const f32x4*)p;
    f32x4 v1 = *(const f32x4*)(p + 4);
    bf16x8 r;
    r[0] = f2bf(v0[0]); r[1] = f2bf(v0[1]); r[2] = f2bf(v0[2]); r[3] = f2bf(v0[3]);
    r[4] = f2bf(v1[0]); r[5] = f2bf(v1[1]); r[6] = f2bf(v1[2]); r[7] = f2bf(v1[3]);
    return r;
}

// One wave per block; each wave computes a 64x64 tile of f.c^T via 4x4 grid of
// 16x16x32 bf16 MFMAs (K=128 -> 4 k-steps). fp32 inputs converted to bf16
// in-register (working set ~1.3 MB, L2-resident).
// Grid: 512 = 32 row-tiles x 16 col-tiles (cols padded 1000->1024, masked).
__global__ __launch_bounds__(64) void lgm_main_kernel(
    const float* __restrict__ feat,
    const float* __restrict__ centers,
    const int* __restrict__ label,
    const float* __restrict__ ws,
    float* __restrict__ out)
{
    const float* fn = ws + WS_FN;
    const float* cn = ws + WS_CN;

    int lane    = threadIdx.x;      // 0..63
    int tileCol = blockIdx.x & 15;
    int tileRow = blockIdx.x >> 4;
    int rowBase = tileRow * 64;
    int colBase = tileCol * 64;
    int quad    = lane >> 4;        // 0..3
    int l15     = lane & 15;        // 0..15

    f32x4 acc[4][4];
    #pragma unroll
    for (int rt = 0; rt < 4; rt++)
        #pragma unroll
        for (int ct = 0; ct < 4; ct++)
            acc[rt][ct] = (f32x4){0.f, 0.f, 0.f, 0.f};

    #pragma unroll
    for (int kk = 0; kk < 4; kk++) {
        int kOff = kk * 32 + quad * 8;   // A[m=lane&15][k=quad*8+j], j in [0,8)
        bf16x8 a[4], b[4];
        #pragma unroll
        for (int rt = 0; rt < 4; rt++) {
            int r = rowBase + rt * 16 + l15;
            a[rt] = load_cvt8(feat + r * FEAT + kOff);
        }
        #pragma unroll
        for (int ct = 0; ct < 4; ct++) {
            int c = colBase + ct * 16 + l15;               // B^T[n=lane&15][k]
            c = (c < NCLS) ? c : (NCLS - 1);               // clamp; masked at store
            b[ct] = load_cvt8(centers + c * FEAT + kOff);
        }
        #pragma unroll
        for (int rt = 0; rt < 4; rt++)
            #pragma unroll
            for (int ct = 0; ct < 4; ct++)
                acc[rt][ct] = __builtin_amdgcn_mfma_f32_16x16x32_bf16(
                    a[rt], b[ct], acc[rt][ct], 0, 0, 0);
    }

    // Epilogue: D mapping col = lane&15, row = quad*4 + reg (m89-verified)
    float* out0 = out;                    // logits        [2048,1000] fp32
    float* out1 = out + BATCH * NCLS;     // margin_logits [2048,1000] fp32
    #pragma unroll
    for (int rt = 0; rt < 4; rt++) {
        #pragma unroll
        for (int reg = 0; reg < 4; reg++) {
            int row   = rowBase + rt * 16 + quad * 4 + reg;
            float fnr = fn[row];
            int   lb  = label[row];
            #pragma unroll
            for (int ct = 0; ct < 4; ct++) {
                int col = colBase + ct * 16 + l15;
                if (col < NCLS) {
                    float dot   = acc[rt][ct][reg];
                    float dist  = fnr + cn[col] - 2.0f * dot;
                    float logit = -0.5f * dist;
                    int idx = row * NCLS + col;
                    out0[idx] = logit;
                    out1[idx] = (col == lb) ? 2.0f * logit : logit;
                }
            }
        }
    }

    if (blockIdx.x == 0 && lane == 0) {
        out[2 * BATCH * NCLS] = ws[0];    // likelihood, fp32
    }
}

extern "C" void kernel_launch(void* const* d_in, const int* in_sizes, int n_in,
                              void* d_out, int out_size, void* d_ws, size_t ws_size,
                              hipStream_t stream) {
    const float* feat    = (const float*)d_in[0];
    const int*   label   = (const int*)d_in[1];
    const float* centers = (const float*)d_in[2];
    float* ws = (float*)d_ws;

    // zero the likelihood accumulator (harness poisons ws with 0xAA)
    hipMemsetAsync(d_ws, 0, 4, stream);

    // 3048 waves: 2048 feat rows (norm + likelihood), 1000 center rows (norm)
    prep_kernel<<<762, 256, 0, stream>>>(feat, centers, label, ws);

    lgm_main_kernel<<<512, 64, 0, stream>>>(feat, centers, label, ws, (float*)d_out);
}

// Round 5
// 74.323 us; speedup vs baseline: 1.4635x; 1.4635x over previous
//
#include <hip/hip_runtime.h>
#include <hip/hip_bf16.h>

#define BATCH 2048
#define NCLS  1000
#define FEAT  128

typedef short bf16x8 __attribute__((ext_vector_type(8)));
typedef float f32x16 __attribute__((ext_vector_type(16)));

// ws float layout (14.2 KB):
//   [0    .. 512)   likelihood block partials (one per prep feat-block)
//   [512  .. 2560)  fn[b] = |feat_b|^2
//   [2560 .. 3560)  cn[c] = |center_c|^2
#define WS_LP   0
#define WS_FN   512
#define WS_CN   2560

__device__ inline short f2bf(float f) {
    unsigned int u;
    __builtin_memcpy(&u, &f, 4);
    unsigned int r = u + 0x7fffu + ((u >> 16) & 1u);   // RNE
    return (short)(r >> 16);
}

__device__ inline bf16x8 load_cvt8(const float* p) {
    typedef float f32x4 __attribute__((ext_vector_type(4)));
    f32x4 v0 = *(const f32x4*)p;
    f32x4 v1 = *(const f32x4*)(p + 4);
    bf16x8 r;
    r[0] = f2bf(v0[0]); r[1] = f2bf(v0[1]); r[2] = f2bf(v0[2]); r[3] = f2bf(v0[3]);
    r[4] = f2bf(v1[0]); r[5] = f2bf(v1[1]); r[6] = f2bf(v1[2]); r[7] = f2bf(v1[3]);
    return r;
}

// One wave per row: w in [0,2048) = feat rows (|f|^2 + likelihood partial),
// w in [2048,3048) = center rows (|c|^2). Blocks 0..511 are pure feat blocks;
// each writes ONE likelihood partial (no atomics — see R4 post-mortem).
__global__ __launch_bounds__(256) void prep_kernel(
    const float* __restrict__ feat,
    const float* __restrict__ centers,
    const int* __restrict__ label,
    float* __restrict__ ws)
{
    __shared__ float lp[4];
    int w    = blockIdx.x * 4 + (threadIdx.x >> 6);
    int lane = threadIdx.x & 63;
    float* fn = ws + WS_FN;
    float* cn = ws + WS_CN;

    if (w < BATCH) {
        int b = w;
        float2 f = *(const float2*)(feat + b * FEAT + lane * 2);
        int lb = label[b];
        float2 c = *(const float2*)(centers + lb * FEAT + lane * 2);
        float fs = f.x * f.x + f.y * f.y;
        float d0 = f.x - c.x, d1 = f.y - c.y;
        float ls = d0 * d0 + d1 * d1;
        #pragma unroll
        for (int off = 32; off > 0; off >>= 1) {
            fs += __shfl_down(fs, off, 64);
            ls += __shfl_down(ls, off, 64);
        }
        if (lane == 0) {
            fn[b] = fs;
            lp[threadIdx.x >> 6] = ls;
        }
    } else if (w < BATCH + NCLS) {
        int c = w - BATCH;
        float2 cv = *(const float2*)(centers + c * FEAT + lane * 2);
        float cs = cv.x * cv.x + cv.y * cv.y;
        #pragma unroll
        for (int off = 32; off > 0; off >>= 1) cs += __shfl_down(cs, off, 64);
        if (lane == 0) cn[c] = cs;
    }

    if (blockIdx.x < 512) {            // block-uniform branch
        __syncthreads();
        if (threadIdx.x == 0)
            ws[WS_LP + blockIdx.x] = lp[0] + lp[1] + lp[2] + lp[3];
    }
}

// 256 threads = 4 waves in a 2x2 grid of 32x32 tiles -> 64x64 block tile.
// Each wave: 8 x mfma_f32_32x32x16_bf16 over K=128. 512 blocks = 2048 waves.
// Block 0 additionally reduces the 512 likelihood partials.
__global__ __launch_bounds__(256) void lgm_main_kernel(
    const float* __restrict__ feat,
    const float* __restrict__ centers,
    const int* __restrict__ label,
    const float* __restrict__ ws,
    float* __restrict__ out)
{
    const float* fn = ws + WS_FN;
    const float* cn = ws + WS_CN;

    int tid     = threadIdx.x;
    int lane    = tid & 63;
    int wave    = tid >> 6;                 // 0..3
    int tileCol = blockIdx.x & 15;
    int tileRow = blockIdx.x >> 4;
    int rowBase = tileRow * 64 + (wave & 1) * 32;
    int colBase = tileCol * 64 + (wave >> 1) * 32;
    int m       = lane & 31;
    int half    = lane >> 5;                // 0..1

    int r  = rowBase + m;                   // A row for this lane
    int c0 = colBase + m;                   // output col for this lane
    int c  = (c0 < NCLS) ? c0 : (NCLS - 1); // clamped for loads

    const float* ap = feat    + r * FEAT + half * 8;
    const float* bp = centers + c * FEAT + half * 8;

    f32x16 acc = {};
    #pragma unroll
    for (int kk = 0; kk < 8; kk++) {        // K=128 in steps of 16
        bf16x8 a = load_cvt8(ap + kk * 16); // A[m=lane&31][k=half*8+j]
        bf16x8 b = load_cvt8(bp + kk * 16); // B^T[n=lane&31][k=half*8+j]
        acc = __builtin_amdgcn_mfma_f32_32x32x16_bf16(a, b, acc, 0, 0, 0);
    }

    // C/D mapping (m74/m101): col = lane&31, row = (reg&3) + 8*(reg>>2) + 4*half
    float* out0 = out;                      // logits        [2048,1000]
    float* out1 = out + BATCH * NCLS;       // margin_logits [2048,1000]
    float cnv = cn[c];
    bool  colOK = (c0 < NCLS);
    #pragma unroll
    for (int reg = 0; reg < 16; reg++) {
        int row = rowBase + (reg & 3) + 8 * (reg >> 2) + 4 * half;
        if (colOK) {
            float dist  = fn[row] + cnv - 2.0f * acc[reg];
            float logit = -0.5f * dist;
            int idx = row * NCLS + c0;
            out0[idx] = logit;
            out1[idx] = (c0 == label[row]) ? 2.0f * logit : logit;
        }
    }

    // Likelihood: sum the 512 prep partials (exactly 8 per lane), one wave.
    if (blockIdx.x == 0 && tid < 64) {
        float s = 0.0f;
        #pragma unroll
        for (int j = 0; j < 8; j++) s += ws[WS_LP + lane + 64 * j];
        #pragma unroll
        for (int off = 32; off > 0; off >>= 1) s += __shfl_down(s, off, 64);
        if (lane == 0) out[2 * BATCH * NCLS] = s * (0.5f / (float)BATCH);
    }
}

extern "C" void kernel_launch(void* const* d_in, const int* in_sizes, int n_in,
                              void* d_out, int out_size, void* d_ws, size_t ws_size,
                              hipStream_t stream) {
    const float* feat    = (const float*)d_in[0];
    const int*   label   = (const int*)d_in[1];
    const float* centers = (const float*)d_in[2];
    float* ws = (float*)d_ws;

    prep_kernel<<<762, 256, 0, stream>>>(feat, centers, label, ws);
    lgm_main_kernel<<<512, 256, 0, stream>>>(feat, centers, label, ws, (float*)d_out);
}

// Round 6
// 71.632 us; speedup vs baseline: 1.5185x; 1.0376x over previous
//
#include <hip/hip_runtime.h>
#include <hip/hip_bf16.h>

#define BATCH 2048
#define NCLS  1000
#define FEAT  128

typedef short bf16x8 __attribute__((ext_vector_type(8)));
typedef float f32x16 __attribute__((ext_vector_type(16)));

// ws float-word layout (careful: feat bf16 copy is 2048*128/2 = 131072 WORDS —
// the R2/R3 corruption bug was undersizing this):
//   [0      .. 512)     likelihood block partials (one per prep feat-block)
//   [512    .. 2560)    fn[b] = |feat_b|^2
//   [2560   .. 3560)    cn[c] = |center_c|^2
//   [4096   .. 135168)  feat bf16 copy    (2048*128 bf16, packed 2/word)
//   [135168 .. 199168)  centers bf16 copy (1000*128 bf16, packed 2/word)
#define WS_LP   0
#define WS_FN   512
#define WS_CN   2560
#define WS_FB   4096
#define WS_CB   135168

__device__ inline unsigned int f2bf(float f) {
    unsigned int u;
    __builtin_memcpy(&u, &f, 4);
    return (u + 0x7fffu + ((u >> 16) & 1u)) >> 16;   // RNE
}

// One wave per row: w in [0,2048) = feat rows (|f|^2, likelihood partial, bf16
// copy), w in [2048,3048) = center rows (|c|^2, bf16 copy). Blocks 0..511 are
// pure feat blocks; each writes ONE likelihood partial (no atomics).
__global__ __launch_bounds__(256) void prep_kernel(
    const float* __restrict__ feat,
    const float* __restrict__ centers,
    const int* __restrict__ label,
    float* __restrict__ ws)
{
    __shared__ float lp[4];
    int w    = blockIdx.x * 4 + (threadIdx.x >> 6);
    int lane = threadIdx.x & 63;
    float* fn = ws + WS_FN;
    float* cn = ws + WS_CN;
    unsigned int* fb = (unsigned int*)(ws + WS_FB);
    unsigned int* cb = (unsigned int*)(ws + WS_CB);

    if (w < BATCH) {
        int b = w;
        float2 f = *(const float2*)(feat + b * FEAT + lane * 2);
        int lb = label[b];
        float2 c = *(const float2*)(centers + lb * FEAT + lane * 2);
        fb[b * 64 + lane] = f2bf(f.x) | (f2bf(f.y) << 16);
        float fs = f.x * f.x + f.y * f.y;
        float d0 = f.x - c.x, d1 = f.y - c.y;
        float ls = d0 * d0 + d1 * d1;
        #pragma unroll
        for (int off = 32; off > 0; off >>= 1) {
            fs += __shfl_down(fs, off, 64);
            ls += __shfl_down(ls, off, 64);
        }
        if (lane == 0) {
            fn[b] = fs;
            lp[threadIdx.x >> 6] = ls;
        }
    } else if (w < BATCH + NCLS) {
        int c = w - BATCH;
        float2 cv = *(const float2*)(centers + c * FEAT + lane * 2);
        cb[c * 64 + lane] = f2bf(cv.x) | (f2bf(cv.y) << 16);
        float cs = cv.x * cv.x + cv.y * cv.y;
        #pragma unroll
        for (int off = 32; off > 0; off >>= 1) cs += __shfl_down(cs, off, 64);
        if (lane == 0) cn[c] = cs;
    }

    if (blockIdx.x < 512) {            // block-uniform branch
        __syncthreads();
        if (threadIdx.x == 0)
            ws[WS_LP + blockIdx.x] = lp[0] + lp[1] + lp[2] + lp[3];
    }
}

// 256 threads = 4 waves in a 2x2 grid of 32x32 tiles -> 64x64 block tile.
// Each wave: 8 x mfma_f32_32x32x16_bf16 over K=128, pure bf16x8 loads (no cvt
// VALU — conversion done once in prep). 512 blocks = 2048 waves.
// Block 0 additionally reduces the 512 likelihood partials.
__global__ __launch_bounds__(256) void lgm_main_kernel(
    const int* __restrict__ label,
    const float* __restrict__ ws,
    float* __restrict__ out)
{
    const float* fn = ws + WS_FN;
    const float* cn = ws + WS_CN;
    const unsigned short* fb = (const unsigned short*)(ws + WS_FB);
    const unsigned short* cb = (const unsigned short*)(ws + WS_CB);

    int tid     = threadIdx.x;
    int lane    = tid & 63;
    int wave    = tid >> 6;                 // 0..3
    int tileCol = blockIdx.x & 15;
    int tileRow = blockIdx.x >> 4;
    int rowBase = tileRow * 64 + (wave & 1) * 32;
    int colBase = tileCol * 64 + (wave >> 1) * 32;
    int m       = lane & 31;
    int half    = lane >> 5;                // 0..1

    int r  = rowBase + m;                   // A row for this lane
    int c0 = colBase + m;                   // output col for this lane
    int c  = (c0 < NCLS) ? c0 : (NCLS - 1); // clamped for loads

    const unsigned short* ap = fb + r * FEAT + half * 8;
    const unsigned short* bp = cb + c * FEAT + half * 8;

    f32x16 acc = {};
    #pragma unroll
    for (int kk = 0; kk < 8; kk++) {        // K=128 in steps of 16
        bf16x8 a = *(const bf16x8*)(ap + kk * 16); // A[m][k=half*8+j]
        bf16x8 b = *(const bf16x8*)(bp + kk * 16); // B^T[n][k=half*8+j]
        acc = __builtin_amdgcn_mfma_f32_32x32x16_bf16(a, b, acc, 0, 0, 0);
    }

    // C/D mapping (m74/m101): col = lane&31, row = (reg&3) + 8*(reg>>2) + 4*half
    float* out0 = out;                      // logits        [2048,1000]
    float* out1 = out + BATCH * NCLS;       // margin_logits [2048,1000]
    float cnv = cn[c];
    bool  colOK = (c0 < NCLS);
    #pragma unroll
    for (int reg = 0; reg < 16; reg++) {
        int row = rowBase + (reg & 3) + 8 * (reg >> 2) + 4 * half;
        if (colOK) {
            float dist  = fn[row] + cnv - 2.0f * acc[reg];
            float logit = -0.5f * dist;
            int idx = row * NCLS + c0;
            out0[idx] = logit;
            out1[idx] = (c0 == label[row]) ? 2.0f * logit : logit;
        }
    }

    // Likelihood: sum the 512 prep partials (exactly 8 per lane), one wave.
    if (blockIdx.x == 0 && tid < 64) {
        float s = 0.0f;
        #pragma unroll
        for (int j = 0; j < 8; j++) s += ws[WS_LP + lane + 64 * j];
        #pragma unroll
        for (int off = 32; off > 0; off >>= 1) s += __shfl_down(s, off, 64);
        if (lane == 0) out[2 * BATCH * NCLS] = s * (0.5f / (float)BATCH);
    }
}

extern "C" void kernel_launch(void* const* d_in, const int* in_sizes, int n_in,
                              void* d_out, int out_size, void* d_ws, size_t ws_size,
                              hipStream_t stream) {
    const float* feat    = (const float*)d_in[0];
    const int*   label   = (const int*)d_in[1];
    const float* centers = (const float*)d_in[2];
    float* ws = (float*)d_ws;

    prep_kernel<<<762, 256, 0, stream>>>(feat, centers, label, ws);
    lgm_main_kernel<<<512, 256, 0, stream>>>(label, ws, (float*)d_out);
}